// Round 12
// baseline (201.837 us; speedup 1.0000x reference)
//
#include <hip/hip_runtime.h>
#include <stdint.h>

#define DIM   2048
#define LSEQ  2048
#define BATCH 2
#define NH    32
#define NKV   8
#define HD    64
#define M_ROWS (BATCH*LSEQ)       // 4096
#define NQKV  (DIM + 2*NKV*HD)    // 3072
#define KOFF  DIM                 // 2048
#define VOFF  (DIM + NKV*HD)      // 2560

typedef __attribute__((ext_vector_type(8))) __bf16 bf16x8;
typedef __attribute__((ext_vector_type(8))) unsigned short u16x8;
typedef __attribute__((ext_vector_type(4))) float f32x4;

// hardware RNE f32->bf16 (harness-verified rounds 2-11)
__device__ __forceinline__ unsigned short f2bf(float f) {
  union { __bf16 h; unsigned short u; } v;
  v.h = (__bf16)f;
  return v.u;
}
__device__ __forceinline__ float bf2f(unsigned short h) {
  union { unsigned u; float f; } v; v.u = ((unsigned)h) << 16;
  return v.f;
}

__device__ __forceinline__ void gload_lds16(const void* g, void* l) {
  __builtin_amdgcn_global_load_lds(
      (__attribute__((address_space(1))) unsigned int*)g,
      (__attribute__((address_space(3))) unsigned int*)l, 16, 0, 0);
}

// ---------------- fp32 -> bf16 convert (vectorized) ----------------
__global__ void k_cvt_x(const float* __restrict__ in, unsigned short* __restrict__ out, int n4) {
  int i = blockIdx.x * blockDim.x + threadIdx.x;
  if (i >= n4) return;
  float4 v = ((const float4*)in)[i];
  ushort4 o;
  o.x = f2bf(v.x); o.y = f2bf(v.y); o.z = f2bf(v.z); o.w = f2bf(v.w);
  ((ushort4*)out)[i] = o;
}

// ---------------- fused weight transposes: 4 launches -> 1 (z-sectioned) ----------------
// sec 0: wq -> wqkvT[0]        (scale = C2, folds softmax 1/sqrt(d)*log2(e))
// sec 1: wk -> wqkvT + 2048*2048 ; sec 2: wv -> wqkvT + 2560*2048 ; sec 3: wo -> woT
// Body identical to the verified k_transpose_bf16; idle x-blocks (N=512 sections) exit.
__global__ void k_transpose_all(const float* __restrict__ wq, const float* __restrict__ wk,
                                const float* __restrict__ wv, const float* __restrict__ wo,
                                unsigned short* __restrict__ wqkvT,
                                unsigned short* __restrict__ woT, float C2) {
  __shared__ float tile[32][33];
  int sec = blockIdx.z;
  const float* in; unsigned short* out; int N; float scale = 1.0f;
  if (sec == 0)      { in = wq; out = wqkvT;                     N = DIM; scale = C2; }
  else if (sec == 1) { in = wk; out = wqkvT + (long)2048 * 2048; N = 512; }
  else if (sec == 2) { in = wv; out = wqkvT + (long)2560 * 2048; N = 512; }
  else               { in = wo; out = woT;                       N = DIM; }
  int n0 = blockIdx.x * 32;
  if (n0 >= N) return;
  int k0 = blockIdx.y * 32;
  int tx = threadIdx.x, ty = threadIdx.y;
  #pragma unroll
  for (int i = ty; i < 32; i += 8)
    tile[i][tx] = in[(long)(k0 + i) * N + n0 + tx];
  __syncthreads();
  #pragma unroll
  for (int i = ty; i < 32; i += 8)
    out[(long)(n0 + i) * DIM + k0 + tx] = f2bf(scale * tile[tx][i]);
}

// ---------------- transpose V section of qkv -> vT, k-PERMUTED columns ----------------
// Column position e holds original k = tx with e = 8*((tx>>2)&3) + 4*(tx>>4) + (tx&3),
// matching flash's in-register-P A-fragment k-order (round 6/7, verified).
__global__ void k_transpose_v(const unsigned short* __restrict__ qkv,
                              unsigned short* __restrict__ vT) {
  __shared__ unsigned short tile[32][33];
  int c0 = blockIdx.x * 32;   // within 512 (= g*64+d)
  int l0 = blockIdx.y * 32;
  int b  = blockIdx.z;
  int tx = threadIdx.x, ty = threadIdx.y;
  #pragma unroll
  for (int i = ty; i < 32; i += 8)
    tile[i][tx] = qkv[((long)b * LSEQ + l0 + i) * NQKV + VOFF + c0 + tx];
  __syncthreads();
  int e = 8 * ((tx >> 2) & 3) + 4 * (tx >> 4) + (tx & 3);
  #pragma unroll
  for (int i = ty; i < 32; i += 8)
    vT[((long)b * 512 + c0 + i) * LSEQ + l0 + e] = tile[tx][i];
}

// ---------------- RoPE tables ----------------
__global__ void k_rope_table(float* __restrict__ cosT, float* __restrict__ sinT) {
  int i = blockIdx.x * 256 + threadIdx.x;  // < LSEQ*32
  int t = i >> 5, j = i & 31;
  float inv = powf(10000.0f, -(float)j / 32.0f);
  float fr = (float)t * inv;
  cosT[i] = cosf(fr);
  sinT[i] = sinf(fr);
}

// ---------------- GEMM v5 (QKV): 128^2 tile, BK=64, swizzled 128B-row LDS ----------------
// Round-10 verified: 68us, MfmaUtil 32, conflicts 0, 3 blocks/CU. RoPE epilogue fused.
// NOT double-buffered: m99/m100 + r11 evidence says dbuf is neutral at 3 blocks/CU
// (implicit wave-level overlap already covers the drain).
template<bool BF16OUT, bool ROPE>
__global__ __launch_bounds__(256) void k_gemm_bt(
    const unsigned short* __restrict__ A, const unsigned short* __restrict__ Bt,
    void* __restrict__ Cv, int M, int N, int K,
    const float* __restrict__ cosT, const float* __restrict__ sinT) {
  __shared__ __align__(16) char AsB[16384];   // [128 rows][128B], swizzled
  __shared__ __align__(16) char BsB[16384];   // [128 rows][128B], swizzled
  int t = threadIdx.x;
  int lane = t & 63, wave = t >> 6;
  int fr = lane & 15, fg = lane >> 4;
  long rowA = (long)blockIdx.x * 128;
  long rowB = (long)blockIdx.y * 128;
  long K2 = (long)K * 2;

  int scol = ((t & 7) * 16) ^ (((t >> 3) & 7) << 4);
  const char* ApB = (const char*)A  + (rowA + (t >> 3)) * K2 + scol;
  const char* BpB = (const char*)Bt + (rowB + (t >> 3)) * K2 + scol;

  f32x4 acc[4][4] = {};
  int wr = (wave >> 1) * 64, wc = (wave & 1) * 64;
  int sw8 = (fr & 7) << 4;

  for (int kt = 0; kt < K; kt += 64) {
    #pragma unroll
    for (int p = 0; p < 4; p++) {
      gload_lds16(ApB + (long)(p * 32) * K2 + kt * 2, AsB + p * 4096 + t * 16);
      gload_lds16(BpB + (long)(p * 32) * K2 + kt * 2, BsB + p * 4096 + t * 16);
    }
    __syncthreads();
    #pragma unroll
    for (int ks = 0; ks < 2; ks++) {
      bf16x8 af[4], bfv[4];
      #pragma unroll
      for (int i = 0; i < 4; i++)
        af[i] = *(const bf16x8*)(AsB + (wr + i * 16 + fr) * 128 + ((ks * 64 + fg * 16) ^ sw8));
      #pragma unroll
      for (int j = 0; j < 4; j++)
        bfv[j] = *(const bf16x8*)(BsB + (wc + j * 16 + fr) * 128 + ((ks * 64 + fg * 16) ^ sw8));
      #pragma unroll
      for (int i = 0; i < 4; i++) {
        #pragma unroll
        for (int j = 0; j < 4; j++)
          acc[i][j] = __builtin_amdgcn_mfma_f32_16x16x32_bf16(af[i], bfv[j], acc[i][j], 0, 0, 0);
      }
    }
    __syncthreads();
  }

  long colbase = rowB + wc;
  bool rope_sec = ROPE && (colbase < VOFF);   // Q or K head (col < 2560); wave-uniform
  #pragma unroll
  for (int i = 0; i < 4; i++) {
    #pragma unroll
    for (int r = 0; r < 4; r++) {
      long row = rowA + wr + i * 16 + fg * 4 + r;
      if (ROPE && rope_sec) {
        int tpos = (int)(row & (LSEQ - 1));
        #pragma unroll
        for (int j = 0; j < 2; j++) {   // pair (d = j*16+fr, d+32 = (j+2)*16+fr)
          int jj = j * 16 + fr;
          float c = cosT[tpos * 32 + jj];
          float s = sinT[tpos * 32 + jj];
          float lo = acc[i][j][r], hi = acc[i][j + 2][r];
          ((unsigned short*)Cv)[row * N + colbase + j * 16 + fr]       = f2bf(lo * c - hi * s);
          ((unsigned short*)Cv)[row * N + colbase + (j + 2) * 16 + fr] = f2bf(hi * c + lo * s);
        }
      } else {
        #pragma unroll
        for (int j = 0; j < 4; j++) {
          long col = colbase + j * 16 + fr;
          if (BF16OUT) ((unsigned short*)Cv)[row * N + col] = f2bf(acc[i][j][r]);
          else         ((float*)Cv)[row * N + col] = acc[i][j][r];
        }
      }
    }
  }
}

// ---------------- GEMM v7 (WO): 64x128 tile + dbuf single-barrier pipeline ----------------
// Round-12: WO at 546 TF is occupancy-starved (grid 512 = 2/CU exactly vs QKV's 3).
// 64x128 tile -> grid 1024, LDS 2x(8K A + 16K B) = 48KB -> 3 blocks/CU resident +
// backfill. Round-9's bare retile regressed on exposed drain; the r11 single-barrier
// pipeline removes that exposure (vmcnt(0) waits loads issued a FULL iteration ago),
// so the occupancy gain should survive. Same verified sw8 both-sides swizzle (A rows
// wr in {0,32}: row&7 == fr&7 holds). WAR audit identical to r11: stage targets the
// buffer whose readers retired before the previous top-of-iter barrier.
__global__ __launch_bounds__(256) void k_gemm_db(
    const unsigned short* __restrict__ A, const unsigned short* __restrict__ Bt,
    float* __restrict__ Cv, int M, int N, int K) {
  __shared__ __align__(16) char AsB[2][8192];    // [buf][64 rows][128B], swizzled
  __shared__ __align__(16) char BsB[2][16384];   // [buf][128 rows][128B], swizzled
  int t = threadIdx.x;
  int lane = t & 63, wave = t >> 6;
  int fr = lane & 15, fg = lane >> 4;
  long rowA = (long)blockIdx.x * 64;
  long rowB = (long)blockIdx.y * 128;
  long K2 = (long)K * 2;

  int scol = ((t & 7) * 16) ^ (((t >> 3) & 7) << 4);
  const char* ApB = (const char*)A  + (rowA + (t >> 3)) * K2 + scol;
  const char* BpB = (const char*)Bt + (rowB + (t >> 3)) * K2 + scol;

  auto stage = [&](int kt, int bi) {   // kt in 64-elem tiles; 6 loads/thread
    #pragma unroll
    for (int p = 0; p < 2; p++)
      gload_lds16(ApB + (long)(p * 32) * K2 + (long)kt * 128, AsB[bi] + p * 4096 + t * 16);
    #pragma unroll
    for (int p = 0; p < 4; p++)
      gload_lds16(BpB + (long)(p * 32) * K2 + (long)kt * 128, BsB[bi] + p * 4096 + t * 16);
  };

  f32x4 acc[2][4] = {};
  int wr = (wave >> 1) * 32, wc = (wave & 1) * 64;   // 2M x 2N quadrants of 32x64
  int sw8 = (fr & 7) << 4;
  int NT = K >> 6;

  stage(0, 0);
  for (int kt = 0; kt < NT; kt++) {
    int cur = kt & 1;
    // tile kt's 6 loads are the only outstanding VMEM; issued a full iteration ago
    asm volatile("s_waitcnt vmcnt(0)" ::: "memory");
    __builtin_amdgcn_s_barrier();
    __builtin_amdgcn_sched_barrier(0);
    const char* Ac = AsB[cur];
    const char* Bc = BsB[cur];
    #pragma unroll
    for (int ks = 0; ks < 2; ks++) {
      bf16x8 af[2], bfv[4];
      #pragma unroll
      for (int i = 0; i < 2; i++)
        af[i] = *(const bf16x8*)(Ac + (wr + i * 16 + fr) * 128 + ((ks * 64 + fg * 16) ^ sw8));
      #pragma unroll
      for (int j = 0; j < 4; j++)
        bfv[j] = *(const bf16x8*)(Bc + (wc + j * 16 + fr) * 128 + ((ks * 64 + fg * 16) ^ sw8));
      if (ks == 0 && kt + 1 < NT) stage(kt + 1, cur ^ 1);   // issue under reads+MFMA
      #pragma unroll
      for (int i = 0; i < 2; i++) {
        #pragma unroll
        for (int j = 0; j < 4; j++)
          acc[i][j] = __builtin_amdgcn_mfma_f32_16x16x32_bf16(af[i], bfv[j], acc[i][j], 0, 0, 0);
      }
    }
    // no trailing barrier: next iter's top barrier orders reads vs. restage
  }

  #pragma unroll
  for (int i = 0; i < 2; i++) {
    #pragma unroll
    for (int j = 0; j < 4; j++) {
      #pragma unroll
      for (int r = 0; r < 4; r++) {
        long row = rowA + wr + i * 16 + fg * 4 + r;
        long col = rowB + wc + j * 16 + fr;
        Cv[row * N + col] = acc[i][j][r];
      }
    }
  }
}

// ---------------- flash attention v16: in-register P (round-7, verified) ----------------
// Swapped QK (mfma(K,Q)) -> P lane-local per q-column; register-only bf16 pack
// (static-index vector inserts -- the round-6 union idiom went to scratch, rule #20);
// V k-order permuted in k_transpose_v to match A-frag slot order; static-max softmax
// (wq pre-scaled into exp2 domain); LDS 48KB -> 3 blocks/CU.
__global__ __launch_bounds__(256, 3) void k_flash_attn13(
    const unsigned short* __restrict__ qkv, const unsigned short* __restrict__ vT,
    unsigned short* __restrict__ attn) {
  int g0 = (int)blockIdx.x;
  int hb = g0 & 63;
  int h = hb & 31, b = hb >> 5;
  int qt = 15 - (g0 >> 6);            // heavy blocks first (backfill smooths the tail)
  int g = h >> 2;
  int t = threadIdx.x, lane = t & 63, wave = t >> 6;
  int fr = lane & 15, fg = lane >> 4;

  __shared__ __align__(16) char KT[16384];              // 16KB: K tile [128 rows][128B], swz
  __shared__ __align__(16) char VT2[2][16384];          // 32KB: V tile [64 rows][256B], swz, dbuf
  long rowbase = (long)b * LSEQ;

  int qbaseA = qt * 128 + wave * 32;
  int qbaseB = qbaseA + 16;

  const unsigned short* qpA = &qkv[(rowbase + qbaseA + fr) * NQKV + h * 64 + fg * 8];
  const unsigned short* qpB = &qkv[(rowbase + qbaseB + fr) * NQKV + h * 64 + fg * 8];
  bf16x8 qfA0 = *(const bf16x8*)(qpA);
  bf16x8 qfA1 = *(const bf16x8*)(qpA + 32);
  bf16x8 qfB0 = *(const bf16x8*)(qpB);
  bf16x8 qfB1 = *(const bf16x8*)(qpB + 32);

  int kcb = ((t & 7) * 16) ^ (((t >> 3) & 7) << 4);    // K: 128B rows, row = p*32 + (t>>3)
  int vcb = ((t & 15) * 16) ^ (((t >> 4) & 7) << 4);   // V: 256B rows, row = p*16 + (t>>4)

  const char* kgb = (const char*)qkv;
  const char* vgb = (const char*)vT;
  long ksrc0 = ((rowbase) * (long)NQKV + KOFF + (long)g * 64) * 2;
  long vsrc0 = (((long)(b * 512 + g * 64)) * LSEQ) * 2;

  auto stageK = [&](int kbase) {
    #pragma unroll
    for (int p = 0; p < 4; p++) {
      int krow = p * 32 + (t >> 3);
      gload_lds16(kgb + ksrc0 + (long)(kbase + krow) * (NQKV * 2) + kcb,
                  KT + p * 4096 + t * 16);
    }
  };
  auto stageV = [&](int kbase, char* dst) {
    #pragma unroll
    for (int p = 0; p < 4; p++) {
      int vrow = p * 16 + (t >> 4);
      gload_lds16(vgb + vsrc0 + (long)vrow * (LSEQ * 2) + kbase * 2 + vcb,
                  dst + p * 4096 + t * 16);
    }
  };

  stageK(0);
  stageV(0, VT2[0]);

  f32x4 poA[4] = {}, poB[4] = {};
  float lA = 0.f, lB = 0.f;   // per-lane partial denominators for q = qbase+fr

  int sw8 = (fr & 7) << 4;

  for (int kt = 0; kt <= qt; kt++) {
    int kbase = kt * 128;
    __syncthreads();   // B1: staged K/V landed; all waves' prev-iter LDS reads done

    // V restage WAR-safe at B1 (prev PV readers of this buffer synced); full-iter cover
    if (kt < qt) stageV(kbase + 128, VT2[(kt + 1) & 1]);

    f32x4 stA[8], stB[8];
    __builtin_amdgcn_s_setprio(1);
    #pragma unroll
    for (int s = 0; s < 8; s++) {
      const char* kr = KT + ((s * 16 + fr) << 7);
      bf16x8 kf0 = *(const bf16x8*)(kr + ((fg * 16) ^ sw8));
      bf16x8 kf1 = *(const bf16x8*)(kr + ((fg * 16 + 64) ^ sw8));
      f32x4 a = {};
      a = __builtin_amdgcn_mfma_f32_16x16x32_bf16(kf0, qfA0, a, 0, 0, 0);
      a = __builtin_amdgcn_mfma_f32_16x16x32_bf16(kf1, qfA1, a, 0, 0, 0);
      stA[s] = a;
      f32x4 c = {};
      c = __builtin_amdgcn_mfma_f32_16x16x32_bf16(kf0, qfB0, c, 0, 0, 0);
      c = __builtin_amdgcn_mfma_f32_16x16x32_bf16(kf1, qfB1, c, 0, 0, 0);
      stB[s] = c;
    }
    __builtin_amdgcn_s_setprio(0);
    __syncthreads();   // B2: all waves' K ds_reads retired -> K restage safe

    if (kt < qt) stageK(kbase + 128);   // lands by next B1; softmax+PV cover

    if (kt == qt) {   // diagonal tile: causal mask (k = kbase+s*16+fg*4+r, q = qbase+fr)
      #pragma unroll
      for (int s = 0; s < 8; s++) {
        #pragma unroll
        for (int r = 0; r < 4; r++) {
          int kp = kbase + s * 16 + fg * 4 + r;
          if (kp > qbaseA + fr) stA[s][r] = -1e30f;
          if (kp > qbaseB + fr) stB[s][r] = -1e30f;
        }
      }
    }

    // softmax (static-max, pre-scaled exp2 domain) + register-only bf16 pack.
    // A-frag slot (fg, j): j=r -> k32 = 4*fg + r ; j=4+r -> k32 = 16 + 4*fg + r.
    bf16x8 paA[4], paB[4];
    #pragma unroll
    for (int km = 0; km < 4; km++) {
      bf16x8 pa, pb;
      #pragma unroll
      for (int r = 0; r < 4; r++) {
        float peA = exp2f(stA[2 * km][r]);
        float pqA = exp2f(stA[2 * km + 1][r]);
        lA += peA + pqA;
        pa[r]     = (__bf16)peA;
        pa[r + 4] = (__bf16)pqA;
        float peB = exp2f(stB[2 * km][r]);
        float pqB = exp2f(stB[2 * km + 1][r]);
        lB += peB + pqB;
        pb[r]     = (__bf16)peB;
        pb[r + 4] = (__bf16)pqB;
      }
      paA[km] = pa;
      paB[km] = pb;
    }

    const char* Vb = VT2[kt & 1];
    __builtin_amdgcn_s_setprio(1);
    #pragma unroll
    for (int km = 0; km < 4; km++) {
      #pragma unroll
      for (int dt = 0; dt < 4; dt++) {
        const char* vr = Vb + ((dt * 16 + fr) << 8);
        bf16x8 vf = *(const bf16x8*)(vr + ((km * 64 + fg * 16) ^ sw8));
        poA[dt] = __builtin_amdgcn_mfma_f32_16x16x32_bf16(paA[km], vf, poA[dt], 0, 0, 0);
        poB[dt] = __builtin_amdgcn_mfma_f32_16x16x32_bf16(paB[km], vf, poB[dt], 0, 0, 0);
      }
    }
    __builtin_amdgcn_s_setprio(0);
    // no trailing barrier: next B1 orders LDS reads vs. restaging
  }

  // denominator: reduce per-lane partials over the fg-group (lanes fr, fr+16, fr+32, fr+48)
  lA += __shfl_xor(lA, 16, 64); lA += __shfl_xor(lA, 32, 64);
  lB += __shfl_xor(lB, 16, 64); lB += __shfl_xor(lB, 32, 64);

  // po[dt][r] is O[q = qbase + fg*4 + r][d = dt*16 + fr]; l for q-local i lives on lanes
  // with fr == i -> fetch via shfl from lane fg*4+r (fg=0 copy).
  #pragma unroll
  for (int r = 0; r < 4; r++) {
    float liA = 1.0f / __shfl(lA, fg * 4 + r, 64);
    float liB = 1.0f / __shfl(lB, fg * 4 + r, 64);
    #pragma unroll
    for (int dt = 0; dt < 4; dt++) {
      attn[(rowbase + qbaseA + fg * 4 + r) * DIM + h * 64 + dt * 16 + fr] = f2bf(poA[dt][r] * liA);
      attn[(rowbase + qbaseB + fg * 4 + r) * DIM + h * 64 + dt * 16 + fr] = f2bf(poB[dt][r] * liB);
    }
  }
}

extern "C" void kernel_launch(void* const* d_in, const int* in_sizes, int n_in,
                              void* d_out, int out_size, void* d_ws, size_t ws_size,
                              hipStream_t stream) {
  const float* x  = (const float*)d_in[0];
  const float* wq = (const float*)d_in[1];
  const float* wk = (const float*)d_in[2];
  const float* wv = (const float*)d_in[3];
  const float* wo = (const float*)d_in[4];

  char* ws = (char*)d_ws;
  unsigned short* xb    = (unsigned short*)(ws);                 // 16.78 MB (reused as vT later)
  unsigned short* wqkvT = (unsigned short*)(ws + 16777216);      // 12.58 MB [3072][2048]
  unsigned short* woT   = (unsigned short*)(ws + 29360128);      //  8.39 MB [2048][2048]
  unsigned short* qkv   = (unsigned short*)(ws + 37748736);      // 25.17 MB [4096][3072]
  unsigned short* attn  = (unsigned short*)(ws + 62914560);      // 16.78 MB [4096][2048]
  float* cosT           = (float*)(ws + 79691776);               // 256 KB
  float* sinT           = (float*)(ws + 79953920);               // 256 KB
  unsigned short* vT    = xb;                                    // alias: xb dead after QKV GEMM

  const float C2 = 0.125f * 1.44269504f;   // 1/sqrt(64) * log2(e), folded into wq

  k_cvt_x<<<8192, 256, 0, stream>>>(x, xb, M_ROWS * DIM / 4);
  dim3 tb(32, 8);
  // fused weight transposes: one launch, 4 z-sections (was 4 launches)
  k_transpose_all<<<dim3(64, 64, 4), tb, 0, stream>>>(wq, wk, wv, wo, wqkvT, woT, C2);
  k_rope_table<<<(LSEQ*32)/256, 256, 0, stream>>>(cosT, sinT);

  // QKV: round-10 single-buffered BK=64 (3 blocks/CU, verified 68us) + fused RoPE
  k_gemm_bt<true, true><<<dim3(M_ROWS/128, NQKV/128), 256, 0, stream>>>(
      xb, wqkvT, qkv, M_ROWS, NQKV, DIM, cosT, sinT);
  k_transpose_v<<<dim3(16, 64, 2), tb, 0, stream>>>(qkv, vT);
  k_flash_attn13<<<1024, 256, 0, stream>>>(qkv, vT, attn);
  // WO: 64x128-tile dbuf single-barrier pipeline (grid 1024, 48KB LDS -> 3 blocks/CU)
  k_gemm_db<<<dim3(M_ROWS/64, DIM/128), 256, 0, stream>>>(
      attn, woT, (float*)d_out, M_ROWS, DIM, DIM);
}

// Round 13
// 175.354 us; speedup vs baseline: 1.1510x; 1.1510x over previous
//
#include <hip/hip_runtime.h>
#include <stdint.h>

#define DIM   2048
#define LSEQ  2048
#define BATCH 2
#define NH    32
#define NKV   8
#define HD    64
#define M_ROWS (BATCH*LSEQ)       // 4096
#define NQKV  (DIM + 2*NKV*HD)    // 3072
#define KOFF  DIM                 // 2048
#define VOFF  (DIM + NKV*HD)      // 2560

typedef __attribute__((ext_vector_type(8))) __bf16 bf16x8;
typedef __attribute__((ext_vector_type(8))) unsigned short u16x8;
typedef __attribute__((ext_vector_type(4))) float f32x4;

// hardware RNE f32->bf16 (harness-verified rounds 2-12)
__device__ __forceinline__ unsigned short f2bf(float f) {
  union { __bf16 h; unsigned short u; } v;
  v.h = (__bf16)f;
  return v.u;
}
__device__ __forceinline__ float bf2f(unsigned short h) {
  union { unsigned u; float f; } v; v.u = ((unsigned)h) << 16;
  return v.f;
}

__device__ __forceinline__ void gload_lds16(const void* g, void* l) {
  __builtin_amdgcn_global_load_lds(
      (__attribute__((address_space(1))) unsigned int*)g,
      (__attribute__((address_space(3))) unsigned int*)l, 16, 0, 0);
}

// ---------------- fp32 -> bf16 convert (vectorized) ----------------
__global__ void k_cvt_x(const float* __restrict__ in, unsigned short* __restrict__ out, int n4) {
  int i = blockIdx.x * blockDim.x + threadIdx.x;
  if (i >= n4) return;
  float4 v = ((const float4*)in)[i];
  ushort4 o;
  o.x = f2bf(v.x); o.y = f2bf(v.y); o.z = f2bf(v.z); o.w = f2bf(v.w);
  ((ushort4*)out)[i] = o;
}

// ---------------- fused weight transposes: 4 launches -> 1 (z-sectioned) ----------------
__global__ void k_transpose_all(const float* __restrict__ wq, const float* __restrict__ wk,
                                const float* __restrict__ wv, const float* __restrict__ wo,
                                unsigned short* __restrict__ wqkvT,
                                unsigned short* __restrict__ woT, float C2) {
  __shared__ float tile[32][33];
  int sec = blockIdx.z;
  const float* in; unsigned short* out; int N; float scale = 1.0f;
  if (sec == 0)      { in = wq; out = wqkvT;                     N = DIM; scale = C2; }
  else if (sec == 1) { in = wk; out = wqkvT + (long)2048 * 2048; N = 512; }
  else if (sec == 2) { in = wv; out = wqkvT + (long)2560 * 2048; N = 512; }
  else               { in = wo; out = woT;                       N = DIM; }
  int n0 = blockIdx.x * 32;
  if (n0 >= N) return;
  int k0 = blockIdx.y * 32;
  int tx = threadIdx.x, ty = threadIdx.y;
  #pragma unroll
  for (int i = ty; i < 32; i += 8)
    tile[i][tx] = in[(long)(k0 + i) * N + n0 + tx];
  __syncthreads();
  #pragma unroll
  for (int i = ty; i < 32; i += 8)
    out[(long)(n0 + i) * DIM + k0 + tx] = f2bf(scale * tile[tx][i]);
}

// ---------------- transpose V section of qkv -> vT, k-PERMUTED columns ----------------
// Column position e holds original k = tx with e = 8*((tx>>2)&3) + 4*(tx>>4) + (tx&3),
// matching flash's in-register-P A-fragment k-order (round 6/7, verified).
__global__ void k_transpose_v(const unsigned short* __restrict__ qkv,
                              unsigned short* __restrict__ vT) {
  __shared__ unsigned short tile[32][33];
  int c0 = blockIdx.x * 32;   // within 512 (= g*64+d)
  int l0 = blockIdx.y * 32;
  int b  = blockIdx.z;
  int tx = threadIdx.x, ty = threadIdx.y;
  #pragma unroll
  for (int i = ty; i < 32; i += 8)
    tile[i][tx] = qkv[((long)b * LSEQ + l0 + i) * NQKV + VOFF + c0 + tx];
  __syncthreads();
  int e = 8 * ((tx >> 2) & 3) + 4 * (tx >> 4) + (tx & 3);
  #pragma unroll
  for (int i = ty; i < 32; i += 8)
    vT[((long)b * 512 + c0 + i) * LSEQ + l0 + e] = tile[tx][i];
}

// ---------------- RoPE tables ----------------
__global__ void k_rope_table(float* __restrict__ cosT, float* __restrict__ sinT) {
  int i = blockIdx.x * 256 + threadIdx.x;  // < LSEQ*32
  int t = i >> 5, j = i & 31;
  float inv = powf(10000.0f, -(float)j / 32.0f);
  float fr = (float)t * inv;
  cosT[i] = cosf(fr);
  sinT[i] = sinf(fr);
}

// ---------------- GEMM v8 (QKV): 128^2 tile, BK=64, 512 threads / 8 waves ----------------
// Round-13: tile-size reductions (r9, r12) keep failing on per-iteration overhead --
// so raise waves/SIMD at CONSTANT tile: 512 threads, 8 waves as 4M x 2N (32x64 each).
// Per-block MFMA per K-step unchanged (128 instr); loads/thread halve (4); acc shrinks
// to [2][4] -> lower VGPR. Waves/CU 12 -> 16+ hides the per-iter staging drain.
// Wave col-span 64 stays head-aligned -> RoPE epilogue identical (r8/r9-verified
// formula). Read rows stay fr (mod 8) -> same both-sides XOR swizzle (0 conflicts r10).
template<bool BF16OUT, bool ROPE>
__global__ __launch_bounds__(512, 4) void k_gemm_bt(
    const unsigned short* __restrict__ A, const unsigned short* __restrict__ Bt,
    void* __restrict__ Cv, int M, int N, int K,
    const float* __restrict__ cosT, const float* __restrict__ sinT) {
  __shared__ __align__(16) char AsB[16384];   // [128 rows][128B], swizzled
  __shared__ __align__(16) char BsB[16384];
  int t = threadIdx.x;
  int lane = t & 63, wave = t >> 6;        // 0..7
  int fr = lane & 15, fg = lane >> 4;
  int wm = wave >> 1, wn = wave & 1;       // 4M x 2N quadrants: 32 rows x 64 cols
  long rowA = (long)blockIdx.x * 128;
  long rowB = (long)blockIdx.y * 128;
  long K2 = (long)K * 2;

  // staging: thread t covers rows (t>>3) and (t>>3)+64, 16B granule (t&7);
  // source col-byte inverse-swizzled (rule #21), row&7 == (t>>3)&7 for both rows.
  int scol = ((t & 7) * 16) ^ (((t >> 3) & 7) << 4);
  const char* ApB = (const char*)A  + (rowA + (t >> 3)) * K2 + scol;
  const char* BpB = (const char*)Bt + (rowB + (t >> 3)) * K2 + scol;

  f32x4 acc[2][4] = {};
  int sw8 = (fr & 7) << 4;

  for (int kt = 0; kt < K; kt += 64) {
    #pragma unroll
    for (int p = 0; p < 2; p++) {
      gload_lds16(ApB + (long)(p * 64) * K2 + kt * 2, AsB + p * 8192 + t * 16);
      gload_lds16(BpB + (long)(p * 64) * K2 + kt * 2, BsB + p * 8192 + t * 16);
    }
    __syncthreads();
    #pragma unroll
    for (int ks = 0; ks < 2; ks++) {
      bf16x8 af[2], bfv[4];
      #pragma unroll
      for (int i = 0; i < 2; i++)
        af[i] = *(const bf16x8*)(AsB + (wm * 32 + i * 16 + fr) * 128 + ((ks * 64 + fg * 16) ^ sw8));
      #pragma unroll
      for (int j = 0; j < 4; j++)
        bfv[j] = *(const bf16x8*)(BsB + (wn * 64 + j * 16 + fr) * 128 + ((ks * 64 + fg * 16) ^ sw8));
      #pragma unroll
      for (int i = 0; i < 2; i++) {
        #pragma unroll
        for (int j = 0; j < 4; j++)
          acc[i][j] = __builtin_amdgcn_mfma_f32_16x16x32_bf16(af[i], bfv[j], acc[i][j], 0, 0, 0);
      }
    }
    __syncthreads();
  }

  long colbase = rowB + wn * 64;
  bool rope_sec = ROPE && (colbase < VOFF);   // Q or K head (col < 2560); wave-uniform
  #pragma unroll
  for (int i = 0; i < 2; i++) {
    #pragma unroll
    for (int r = 0; r < 4; r++) {
      long row = rowA + wm * 32 + i * 16 + fg * 4 + r;
      if (ROPE && rope_sec) {
        int tpos = (int)(row & (LSEQ - 1));
        #pragma unroll
        for (int j = 0; j < 2; j++) {   // pair (d = j*16+fr, d+32 = (j+2)*16+fr)
          int jj = j * 16 + fr;
          float c = cosT[tpos * 32 + jj];
          float s = sinT[tpos * 32 + jj];
          float lo = acc[i][j][r], hi = acc[i][j + 2][r];
          ((unsigned short*)Cv)[row * N + colbase + j * 16 + fr]       = f2bf(lo * c - hi * s);
          ((unsigned short*)Cv)[row * N + colbase + (j + 2) * 16 + fr] = f2bf(hi * c + lo * s);
        }
      } else {
        #pragma unroll
        for (int j = 0; j < 4; j++) {
          long col = colbase + j * 16 + fr;
          if (BF16OUT) ((unsigned short*)Cv)[row * N + col] = f2bf(acc[i][j][r]);
          else         ((float*)Cv)[row * N + col] = acc[i][j][r];
        }
      }
    }
  }
}

// ---------------- GEMM v9 (WO): 128^2 dbuf single-barrier pipeline, 512 threads ----------------
// Round-13: revert r12's 64x128 retile (regressed, same mode as r9: halved work per
// barrier-iteration). Back to the r11-verified 128^2 dbuf single-barrier structure,
// with 512 threads / 8 waves (4M x 2N): waves/CU 8 -> 16 at the same 2-blocks/CU grid
// cap. Per-iter per-block MFMA unchanged; loads/thread 8 -> 4. WAR/vmcnt audit as r11:
// the only outstanding VMEM at each top-of-iter wait is tile kt's 4 loads (issued a
// full iteration earlier); stage targets the buffer whose readers retired before the
// previous top barrier.
__global__ __launch_bounds__(512, 4) void k_gemm_db(
    const unsigned short* __restrict__ A, const unsigned short* __restrict__ Bt,
    float* __restrict__ Cv, int M, int N, int K) {
  __shared__ __align__(16) char AsB[2][16384];   // [buf][128 rows][128B], swizzled
  __shared__ __align__(16) char BsB[2][16384];
  int t = threadIdx.x;
  int lane = t & 63, wave = t >> 6;
  int fr = lane & 15, fg = lane >> 4;
  int wm = wave >> 1, wn = wave & 1;       // 4M x 2N quadrants: 32 rows x 64 cols
  long rowA = (long)blockIdx.x * 128;
  long rowB = (long)blockIdx.y * 128;
  long K2 = (long)K * 2;

  int scol = ((t & 7) * 16) ^ (((t >> 3) & 7) << 4);
  const char* ApB = (const char*)A  + (rowA + (t >> 3)) * K2 + scol;
  const char* BpB = (const char*)Bt + (rowB + (t >> 3)) * K2 + scol;

  auto stage = [&](int kt, int bi) {   // kt in 64-elem tiles; 4 loads/thread
    #pragma unroll
    for (int p = 0; p < 2; p++) {
      gload_lds16(ApB + (long)(p * 64) * K2 + (long)kt * 128, AsB[bi] + p * 8192 + t * 16);
      gload_lds16(BpB + (long)(p * 64) * K2 + (long)kt * 128, BsB[bi] + p * 8192 + t * 16);
    }
  };

  f32x4 acc[2][4] = {};
  int sw8 = (fr & 7) << 4;
  int NT = K >> 6;

  stage(0, 0);
  for (int kt = 0; kt < NT; kt++) {
    int cur = kt & 1;
    // tile kt's 4 loads are the only outstanding VMEM; issued a full iteration ago
    asm volatile("s_waitcnt vmcnt(0)" ::: "memory");
    __builtin_amdgcn_s_barrier();
    __builtin_amdgcn_sched_barrier(0);
    const char* Ac = AsB[cur];
    const char* Bc = BsB[cur];
    #pragma unroll
    for (int ks = 0; ks < 2; ks++) {
      bf16x8 af[2], bfv[4];
      #pragma unroll
      for (int i = 0; i < 2; i++)
        af[i] = *(const bf16x8*)(Ac + (wm * 32 + i * 16 + fr) * 128 + ((ks * 64 + fg * 16) ^ sw8));
      #pragma unroll
      for (int j = 0; j < 4; j++)
        bfv[j] = *(const bf16x8*)(Bc + (wn * 64 + j * 16 + fr) * 128 + ((ks * 64 + fg * 16) ^ sw8));
      if (ks == 0 && kt + 1 < NT) stage(kt + 1, cur ^ 1);   // issue under reads+MFMA
      #pragma unroll
      for (int i = 0; i < 2; i++) {
        #pragma unroll
        for (int j = 0; j < 4; j++)
          acc[i][j] = __builtin_amdgcn_mfma_f32_16x16x32_bf16(af[i], bfv[j], acc[i][j], 0, 0, 0);
      }
    }
    // no trailing barrier: next iter's top barrier orders reads vs. restage
  }

  #pragma unroll
  for (int i = 0; i < 2; i++) {
    #pragma unroll
    for (int j = 0; j < 4; j++) {
      #pragma unroll
      for (int r = 0; r < 4; r++) {
        long row = rowA + wm * 32 + i * 16 + fg * 4 + r;
        long col = rowB + wn * 64 + j * 16 + fr;
        Cv[row * N + col] = acc[i][j][r];
      }
    }
  }
}

// ---------------- flash attention v16: in-register P (round-7, verified) ----------------
// Swapped QK (mfma(K,Q)) -> P lane-local per q-column; register-only bf16 pack
// (static-index vector inserts -- the round-6 union idiom went to scratch, rule #20);
// V k-order permuted in k_transpose_v to match A-frag slot order; static-max softmax
// (wq pre-scaled into exp2 domain); LDS 48KB -> 3 blocks/CU.
__global__ __launch_bounds__(256, 3) void k_flash_attn13(
    const unsigned short* __restrict__ qkv, const unsigned short* __restrict__ vT,
    unsigned short* __restrict__ attn) {
  int g0 = (int)blockIdx.x;
  int hb = g0 & 63;
  int h = hb & 31, b = hb >> 5;
  int qt = 15 - (g0 >> 6);            // heavy blocks first (backfill smooths the tail)
  int g = h >> 2;
  int t = threadIdx.x, lane = t & 63, wave = t >> 6;
  int fr = lane & 15, fg = lane >> 4;

  __shared__ __align__(16) char KT[16384];              // 16KB: K tile [128 rows][128B], swz
  __shared__ __align__(16) char VT2[2][16384];          // 32KB: V tile [64 rows][256B], swz, dbuf
  long rowbase = (long)b * LSEQ;

  int qbaseA = qt * 128 + wave * 32;
  int qbaseB = qbaseA + 16;

  const unsigned short* qpA = &qkv[(rowbase + qbaseA + fr) * NQKV + h * 64 + fg * 8];
  const unsigned short* qpB = &qkv[(rowbase + qbaseB + fr) * NQKV + h * 64 + fg * 8];
  bf16x8 qfA0 = *(const bf16x8*)(qpA);
  bf16x8 qfA1 = *(const bf16x8*)(qpA + 32);
  bf16x8 qfB0 = *(const bf16x8*)(qpB);
  bf16x8 qfB1 = *(const bf16x8*)(qpB + 32);

  int kcb = ((t & 7) * 16) ^ (((t >> 3) & 7) << 4);    // K: 128B rows, row = p*32 + (t>>3)
  int vcb = ((t & 15) * 16) ^ (((t >> 4) & 7) << 4);   // V: 256B rows, row = p*16 + (t>>4)

  const char* kgb = (const char*)qkv;
  const char* vgb = (const char*)vT;
  long ksrc0 = ((rowbase) * (long)NQKV + KOFF + (long)g * 64) * 2;
  long vsrc0 = (((long)(b * 512 + g * 64)) * LSEQ) * 2;

  auto stageK = [&](int kbase) {
    #pragma unroll
    for (int p = 0; p < 4; p++) {
      int krow = p * 32 + (t >> 3);
      gload_lds16(kgb + ksrc0 + (long)(kbase + krow) * (NQKV * 2) + kcb,
                  KT + p * 4096 + t * 16);
    }
  };
  auto stageV = [&](int kbase, char* dst) {
    #pragma unroll
    for (int p = 0; p < 4; p++) {
      int vrow = p * 16 + (t >> 4);
      gload_lds16(vgb + vsrc0 + (long)vrow * (LSEQ * 2) + kbase * 2 + vcb,
                  dst + p * 4096 + t * 16);
    }
  };

  stageK(0);
  stageV(0, VT2[0]);

  f32x4 poA[4] = {}, poB[4] = {};
  float lA = 0.f, lB = 0.f;   // per-lane partial denominators for q = qbase+fr

  int sw8 = (fr & 7) << 4;

  for (int kt = 0; kt <= qt; kt++) {
    int kbase = kt * 128;
    __syncthreads();   // B1: staged K/V landed; all waves' prev-iter LDS reads done

    // V restage WAR-safe at B1 (prev PV readers of this buffer synced); full-iter cover
    if (kt < qt) stageV(kbase + 128, VT2[(kt + 1) & 1]);

    f32x4 stA[8], stB[8];
    __builtin_amdgcn_s_setprio(1);
    #pragma unroll
    for (int s = 0; s < 8; s++) {
      const char* kr = KT + ((s * 16 + fr) << 7);
      bf16x8 kf0 = *(const bf16x8*)(kr + ((fg * 16) ^ sw8));
      bf16x8 kf1 = *(const bf16x8*)(kr + ((fg * 16 + 64) ^ sw8));
      f32x4 a = {};
      a = __builtin_amdgcn_mfma_f32_16x16x32_bf16(kf0, qfA0, a, 0, 0, 0);
      a = __builtin_amdgcn_mfma_f32_16x16x32_bf16(kf1, qfA1, a, 0, 0, 0);
      stA[s] = a;
      f32x4 c = {};
      c = __builtin_amdgcn_mfma_f32_16x16x32_bf16(kf0, qfB0, c, 0, 0, 0);
      c = __builtin_amdgcn_mfma_f32_16x16x32_bf16(kf1, qfB1, c, 0, 0, 0);
      stB[s] = c;
    }
    __builtin_amdgcn_s_setprio(0);
    __syncthreads();   // B2: all waves' K ds_reads retired -> K restage safe

    if (kt < qt) stageK(kbase + 128);   // lands by next B1; softmax+PV cover

    if (kt == qt) {   // diagonal tile: causal mask (k = kbase+s*16+fg*4+r, q = qbase+fr)
      #pragma unroll
      for (int s = 0; s < 8; s++) {
        #pragma unroll
        for (int r = 0; r < 4; r++) {
          int kp = kbase + s * 16 + fg * 4 + r;
          if (kp > qbaseA + fr) stA[s][r] = -1e30f;
          if (kp > qbaseB + fr) stB[s][r] = -1e30f;
        }
      }
    }

    // softmax (static-max, pre-scaled exp2 domain) + register-only bf16 pack.
    // A-frag slot (fg, j): j=r -> k32 = 4*fg + r ; j=4+r -> k32 = 16 + 4*fg + r.
    bf16x8 paA[4], paB[4];
    #pragma unroll
    for (int km = 0; km < 4; km++) {
      bf16x8 pa, pb;
      #pragma unroll
      for (int r = 0; r < 4; r++) {
        float peA = exp2f(stA[2 * km][r]);
        float pqA = exp2f(stA[2 * km + 1][r]);
        lA += peA + pqA;
        pa[r]     = (__bf16)peA;
        pa[r + 4] = (__bf16)pqA;
        float peB = exp2f(stB[2 * km][r]);
        float pqB = exp2f(stB[2 * km + 1][r]);
        lB += peB + pqB;
        pb[r]     = (__bf16)peB;
        pb[r + 4] = (__bf16)pqB;
      }
      paA[km] = pa;
      paB[km] = pb;
    }

    const char* Vb = VT2[kt & 1];
    __builtin_amdgcn_s_setprio(1);
    #pragma unroll
    for (int km = 0; km < 4; km++) {
      #pragma unroll
      for (int dt = 0; dt < 4; dt++) {
        const char* vr = Vb + ((dt * 16 + fr) << 8);
        bf16x8 vf = *(const bf16x8*)(vr + ((km * 64 + fg * 16) ^ sw8));
        poA[dt] = __builtin_amdgcn_mfma_f32_16x16x32_bf16(paA[km], vf, poA[dt], 0, 0, 0);
        poB[dt] = __builtin_amdgcn_mfma_f32_16x16x32_bf16(paB[km], vf, poB[dt], 0, 0, 0);
      }
    }
    __builtin_amdgcn_s_setprio(0);
    // no trailing barrier: next B1 orders LDS reads vs. restaging
  }

  // denominator: reduce per-lane partials over the fg-group (lanes fr, fr+16, fr+32, fr+48)
  lA += __shfl_xor(lA, 16, 64); lA += __shfl_xor(lA, 32, 64);
  lB += __shfl_xor(lB, 16, 64); lB += __shfl_xor(lB, 32, 64);

  // po[dt][r] is O[q = qbase + fg*4 + r][d = dt*16 + fr]; l for q-local i lives on lanes
  // with fr == i -> fetch via shfl from lane fg*4+r (fg=0 copy).
  #pragma unroll
  for (int r = 0; r < 4; r++) {
    float liA = 1.0f / __shfl(lA, fg * 4 + r, 64);
    float liB = 1.0f / __shfl(lB, fg * 4 + r, 64);
    #pragma unroll
    for (int dt = 0; dt < 4; dt++) {
      attn[(rowbase + qbaseA + fg * 4 + r) * DIM + h * 64 + dt * 16 + fr] = f2bf(poA[dt][r] * liA);
      attn[(rowbase + qbaseB + fg * 4 + r) * DIM + h * 64 + dt * 16 + fr] = f2bf(poB[dt][r] * liB);
    }
  }
}

extern "C" void kernel_launch(void* const* d_in, const int* in_sizes, int n_in,
                              void* d_out, int out_size, void* d_ws, size_t ws_size,
                              hipStream_t stream) {
  const float* x  = (const float*)d_in[0];
  const float* wq = (const float*)d_in[1];
  const float* wk = (const float*)d_in[2];
  const float* wv = (const float*)d_in[3];
  const float* wo = (const float*)d_in[4];

  char* ws = (char*)d_ws;
  unsigned short* xb    = (unsigned short*)(ws);                 // 16.78 MB (reused as vT later)
  unsigned short* wqkvT = (unsigned short*)(ws + 16777216);      // 12.58 MB [3072][2048]
  unsigned short* woT   = (unsigned short*)(ws + 29360128);      //  8.39 MB [2048][2048]
  unsigned short* qkv   = (unsigned short*)(ws + 37748736);      // 25.17 MB [4096][3072]
  unsigned short* attn  = (unsigned short*)(ws + 62914560);      // 16.78 MB [4096][2048]
  float* cosT           = (float*)(ws + 79691776);               // 256 KB
  float* sinT           = (float*)(ws + 79953920);               // 256 KB
  unsigned short* vT    = xb;                                    // alias: xb dead after QKV GEMM

  const float C2 = 0.125f * 1.44269504f;   // 1/sqrt(64) * log2(e), folded into wq

  k_cvt_x<<<8192, 256, 0, stream>>>(x, xb, M_ROWS * DIM / 4);
  dim3 tb(32, 8);
  // fused weight transposes: one launch, 4 z-sections
  k_transpose_all<<<dim3(64, 64, 4), tb, 0, stream>>>(wq, wk, wv, wo, wqkvT, woT, C2);
  k_rope_table<<<(LSEQ*32)/256, 256, 0, stream>>>(cosT, sinT);

  // QKV: 128^2 BK=64, 512 threads / 8 waves (3 blocks/CU grid, 24 waves/CU target)
  k_gemm_bt<true, true><<<dim3(M_ROWS/128, NQKV/128), 512, 0, stream>>>(
      xb, wqkvT, qkv, M_ROWS, NQKV, DIM, cosT, sinT);
  k_transpose_v<<<dim3(16, 64, 2), tb, 0, stream>>>(qkv, vT);
  k_flash_attn13<<<1024, 256, 0, stream>>>(qkv, vT, attn);
  // WO: r11 128^2 dbuf single-barrier pipeline, 512 threads (2 blocks/CU, 16 waves/CU)
  k_gemm_db<<<dim3(M_ROWS/128, DIM/128), 512, 0, stream>>>(
      attn, woT, (float*)d_out, M_ROWS, DIM, DIM);
}

// Round 14
// 174.977 us; speedup vs baseline: 1.1535x; 1.0022x over previous
//
#include <hip/hip_runtime.h>
#include <stdint.h>

#define DIM   2048
#define LSEQ  2048
#define BATCH 2
#define NH    32
#define NKV   8
#define HD    64
#define M_ROWS (BATCH*LSEQ)       // 4096
#define NQKV  (DIM + 2*NKV*HD)    // 3072
#define KOFF  DIM                 // 2048
#define VOFF  (DIM + NKV*HD)      // 2560

typedef __attribute__((ext_vector_type(8))) __bf16 bf16x8;
typedef __attribute__((ext_vector_type(8))) unsigned short u16x8;
typedef __attribute__((ext_vector_type(4))) float f32x4;

// hardware RNE f32->bf16 (harness-verified rounds 2-13)
__device__ __forceinline__ unsigned short f2bf(float f) {
  union { __bf16 h; unsigned short u; } v;
  v.h = (__bf16)f;
  return v.u;
}
__device__ __forceinline__ float bf2f(unsigned short h) {
  union { unsigned u; float f; } v; v.u = ((unsigned)h) << 16;
  return v.f;
}

__device__ __forceinline__ void gload_lds16(const void* g, void* l) {
  __builtin_amdgcn_global_load_lds(
      (__attribute__((address_space(1))) unsigned int*)g,
      (__attribute__((address_space(3))) unsigned int*)l, 16, 0, 0);
}

// ---------------- fp32 -> bf16 convert (vectorized) ----------------
__global__ void k_cvt_x(const float* __restrict__ in, unsigned short* __restrict__ out, int n4) {
  int i = blockIdx.x * blockDim.x + threadIdx.x;
  if (i >= n4) return;
  float4 v = ((const float4*)in)[i];
  ushort4 o;
  o.x = f2bf(v.x); o.y = f2bf(v.y); o.z = f2bf(v.z); o.w = f2bf(v.w);
  ((ushort4*)out)[i] = o;
}

// ---------------- fused weight transposes: 4 launches -> 1 (z-sectioned) ----------------
__global__ void k_transpose_all(const float* __restrict__ wq, const float* __restrict__ wk,
                                const float* __restrict__ wv, const float* __restrict__ wo,
                                unsigned short* __restrict__ wqkvT,
                                unsigned short* __restrict__ woT, float C2) {
  __shared__ float tile[32][33];
  int sec = blockIdx.z;
  const float* in; unsigned short* out; int N; float scale = 1.0f;
  if (sec == 0)      { in = wq; out = wqkvT;                     N = DIM; scale = C2; }
  else if (sec == 1) { in = wk; out = wqkvT + (long)2048 * 2048; N = 512; }
  else if (sec == 2) { in = wv; out = wqkvT + (long)2560 * 2048; N = 512; }
  else               { in = wo; out = woT;                       N = DIM; }
  int n0 = blockIdx.x * 32;
  if (n0 >= N) return;
  int k0 = blockIdx.y * 32;
  int tx = threadIdx.x, ty = threadIdx.y;
  #pragma unroll
  for (int i = ty; i < 32; i += 8)
    tile[i][tx] = in[(long)(k0 + i) * N + n0 + tx];
  __syncthreads();
  #pragma unroll
  for (int i = ty; i < 32; i += 8)
    out[(long)(n0 + i) * DIM + k0 + tx] = f2bf(scale * tile[tx][i]);
}

// ---------------- transpose V section of qkv -> vT, k-PERMUTED columns ----------------
// Column position e holds original k = tx with e = 8*((tx>>2)&3) + 4*(tx>>4) + (tx&3),
// matching flash's in-register-P A-fragment k-order (round 6/7, verified).
__global__ void k_transpose_v(const unsigned short* __restrict__ qkv,
                              unsigned short* __restrict__ vT) {
  __shared__ unsigned short tile[32][33];
  int c0 = blockIdx.x * 32;   // within 512 (= g*64+d)
  int l0 = blockIdx.y * 32;
  int b  = blockIdx.z;
  int tx = threadIdx.x, ty = threadIdx.y;
  #pragma unroll
  for (int i = ty; i < 32; i += 8)
    tile[i][tx] = qkv[((long)b * LSEQ + l0 + i) * NQKV + VOFF + c0 + tx];
  __syncthreads();
  int e = 8 * ((tx >> 2) & 3) + 4 * (tx >> 4) + (tx & 3);
  #pragma unroll
  for (int i = ty; i < 32; i += 8)
    vT[((long)b * 512 + c0 + i) * LSEQ + l0 + e] = tile[tx][i];
}

// ---------------- RoPE tables ----------------
__global__ void k_rope_table(float* __restrict__ cosT, float* __restrict__ sinT) {
  int i = blockIdx.x * 256 + threadIdx.x;  // < LSEQ*32
  int t = i >> 5, j = i & 31;
  float inv = powf(10000.0f, -(float)j / 32.0f);
  float fr = (float)t * inv;
  cosT[i] = cosf(fr);
  sinT[i] = sinf(fr);
}

// ---------------- GEMM v8 (QKV): 128^2 tile, BK=64, 512 threads / 8 waves (r13, verified) ----------------
template<bool BF16OUT, bool ROPE>
__global__ __launch_bounds__(512, 4) void k_gemm_bt(
    const unsigned short* __restrict__ A, const unsigned short* __restrict__ Bt,
    void* __restrict__ Cv, int M, int N, int K,
    const float* __restrict__ cosT, const float* __restrict__ sinT) {
  __shared__ __align__(16) char AsB[16384];   // [128 rows][128B], swizzled
  __shared__ __align__(16) char BsB[16384];
  int t = threadIdx.x;
  int lane = t & 63, wave = t >> 6;        // 0..7
  int fr = lane & 15, fg = lane >> 4;
  int wm = wave >> 1, wn = wave & 1;       // 4M x 2N quadrants: 32 rows x 64 cols
  long rowA = (long)blockIdx.x * 128;
  long rowB = (long)blockIdx.y * 128;
  long K2 = (long)K * 2;

  int scol = ((t & 7) * 16) ^ (((t >> 3) & 7) << 4);
  const char* ApB = (const char*)A  + (rowA + (t >> 3)) * K2 + scol;
  const char* BpB = (const char*)Bt + (rowB + (t >> 3)) * K2 + scol;

  f32x4 acc[2][4] = {};
  int sw8 = (fr & 7) << 4;

  for (int kt = 0; kt < K; kt += 64) {
    #pragma unroll
    for (int p = 0; p < 2; p++) {
      gload_lds16(ApB + (long)(p * 64) * K2 + kt * 2, AsB + p * 8192 + t * 16);
      gload_lds16(BpB + (long)(p * 64) * K2 + kt * 2, BsB + p * 8192 + t * 16);
    }
    __syncthreads();
    #pragma unroll
    for (int ks = 0; ks < 2; ks++) {
      bf16x8 af[2], bfv[4];
      #pragma unroll
      for (int i = 0; i < 2; i++)
        af[i] = *(const bf16x8*)(AsB + (wm * 32 + i * 16 + fr) * 128 + ((ks * 64 + fg * 16) ^ sw8));
      #pragma unroll
      for (int j = 0; j < 4; j++)
        bfv[j] = *(const bf16x8*)(BsB + (wn * 64 + j * 16 + fr) * 128 + ((ks * 64 + fg * 16) ^ sw8));
      #pragma unroll
      for (int i = 0; i < 2; i++) {
        #pragma unroll
        for (int j = 0; j < 4; j++)
          acc[i][j] = __builtin_amdgcn_mfma_f32_16x16x32_bf16(af[i], bfv[j], acc[i][j], 0, 0, 0);
      }
    }
    __syncthreads();
  }

  long colbase = rowB + wn * 64;
  bool rope_sec = ROPE && (colbase < VOFF);   // Q or K head (col < 2560); wave-uniform
  #pragma unroll
  for (int i = 0; i < 2; i++) {
    #pragma unroll
    for (int r = 0; r < 4; r++) {
      long row = rowA + wm * 32 + i * 16 + fg * 4 + r;
      if (ROPE && rope_sec) {
        int tpos = (int)(row & (LSEQ - 1));
        #pragma unroll
        for (int j = 0; j < 2; j++) {   // pair (d = j*16+fr, d+32 = (j+2)*16+fr)
          int jj = j * 16 + fr;
          float c = cosT[tpos * 32 + jj];
          float s = sinT[tpos * 32 + jj];
          float lo = acc[i][j][r], hi = acc[i][j + 2][r];
          ((unsigned short*)Cv)[row * N + colbase + j * 16 + fr]       = f2bf(lo * c - hi * s);
          ((unsigned short*)Cv)[row * N + colbase + (j + 2) * 16 + fr] = f2bf(hi * c + lo * s);
        }
      } else {
        #pragma unroll
        for (int j = 0; j < 4; j++) {
          long col = colbase + j * 16 + fr;
          if (BF16OUT) ((unsigned short*)Cv)[row * N + col] = f2bf(acc[i][j][r]);
          else         ((float*)Cv)[row * N + col] = acc[i][j][r];
        }
      }
    }
  }
}

// ---------------- GEMM v9 (WO): 128^2 dbuf single-barrier pipeline, 512 threads (r13, verified) ----------------
__global__ __launch_bounds__(512, 4) void k_gemm_db(
    const unsigned short* __restrict__ A, const unsigned short* __restrict__ Bt,
    float* __restrict__ Cv, int M, int N, int K) {
  __shared__ __align__(16) char AsB[2][16384];   // [buf][128 rows][128B], swizzled
  __shared__ __align__(16) char BsB[2][16384];
  int t = threadIdx.x;
  int lane = t & 63, wave = t >> 6;
  int fr = lane & 15, fg = lane >> 4;
  int wm = wave >> 1, wn = wave & 1;       // 4M x 2N quadrants: 32 rows x 64 cols
  long rowA = (long)blockIdx.x * 128;
  long rowB = (long)blockIdx.y * 128;
  long K2 = (long)K * 2;

  int scol = ((t & 7) * 16) ^ (((t >> 3) & 7) << 4);
  const char* ApB = (const char*)A  + (rowA + (t >> 3)) * K2 + scol;
  const char* BpB = (const char*)Bt + (rowB + (t >> 3)) * K2 + scol;

  auto stage = [&](int kt, int bi) {   // kt in 64-elem tiles; 4 loads/thread
    #pragma unroll
    for (int p = 0; p < 2; p++) {
      gload_lds16(ApB + (long)(p * 64) * K2 + (long)kt * 128, AsB[bi] + p * 8192 + t * 16);
      gload_lds16(BpB + (long)(p * 64) * K2 + (long)kt * 128, BsB[bi] + p * 8192 + t * 16);
    }
  };

  f32x4 acc[2][4] = {};
  int sw8 = (fr & 7) << 4;
  int NT = K >> 6;

  stage(0, 0);
  for (int kt = 0; kt < NT; kt++) {
    int cur = kt & 1;
    asm volatile("s_waitcnt vmcnt(0)" ::: "memory");
    __builtin_amdgcn_s_barrier();
    __builtin_amdgcn_sched_barrier(0);
    const char* Ac = AsB[cur];
    const char* Bc = BsB[cur];
    #pragma unroll
    for (int ks = 0; ks < 2; ks++) {
      bf16x8 af[2], bfv[4];
      #pragma unroll
      for (int i = 0; i < 2; i++)
        af[i] = *(const bf16x8*)(Ac + (wm * 32 + i * 16 + fr) * 128 + ((ks * 64 + fg * 16) ^ sw8));
      #pragma unroll
      for (int j = 0; j < 4; j++)
        bfv[j] = *(const bf16x8*)(Bc + (wn * 64 + j * 16 + fr) * 128 + ((ks * 64 + fg * 16) ^ sw8));
      if (ks == 0 && kt + 1 < NT) stage(kt + 1, cur ^ 1);   // issue under reads+MFMA
      #pragma unroll
      for (int i = 0; i < 2; i++) {
        #pragma unroll
        for (int j = 0; j < 4; j++)
          acc[i][j] = __builtin_amdgcn_mfma_f32_16x16x32_bf16(af[i], bfv[j], acc[i][j], 0, 0, 0);
      }
    }
  }

  #pragma unroll
  for (int i = 0; i < 2; i++) {
    #pragma unroll
    for (int j = 0; j < 4; j++) {
      #pragma unroll
      for (int r = 0; r < 4; r++) {
        long row = rowA + wm * 32 + i * 16 + fg * 4 + r;
        long col = rowB + wn * 64 + j * 16 + fr;
        Cv[row * N + col] = acc[i][j][r];
      }
    }
  }
}

// ---------------- flash attention v17: MFMA-computed softmax denominator ----------------
// Round-14: flash is VALU-bound (VALUBusy 58%, MfmaUtil 22%); largest removable VALU
// block is the l accumulation (128 f32 adds/iter) + epilogue shfl reduction. Replace
// with 2 extra MFMA per km: lf = mfma(pa[km], ones, lf) -- row-sums of P on the matrix
// pipe (every output col holds sum_k P[q][k]; C/D layout puts l for q=fg*4+r in lf[r]
// on EVERY lane, exactly matching po's q mapping -> epilogue is just 1/lfA[r], no
// cross-lane traffic). +8 MFMA/iter (~40cy) vs -256 VALU cy/iter. Numerics: l now sums
// bf16-rounded P (same values as the numerator) -- error ~0.006% on the sum, negligible.
// Rest identical to v16 (r7-verified): swapped QK, register-only pack, permuted-V,
// static-max softmax, 48KB LDS, 3 blocks/CU.
__global__ __launch_bounds__(256, 3) void k_flash_attn14(
    const unsigned short* __restrict__ qkv, const unsigned short* __restrict__ vT,
    unsigned short* __restrict__ attn) {
  int g0 = (int)blockIdx.x;
  int hb = g0 & 63;
  int h = hb & 31, b = hb >> 5;
  int qt = 15 - (g0 >> 6);            // heavy blocks first (backfill smooths the tail)
  int g = h >> 2;
  int t = threadIdx.x, lane = t & 63, wave = t >> 6;
  int fr = lane & 15, fg = lane >> 4;

  __shared__ __align__(16) char KT[16384];              // 16KB: K tile [128 rows][128B], swz
  __shared__ __align__(16) char VT2[2][16384];          // 32KB: V tile [64 rows][256B], swz, dbuf
  long rowbase = (long)b * LSEQ;

  int qbaseA = qt * 128 + wave * 32;
  int qbaseB = qbaseA + 16;

  const unsigned short* qpA = &qkv[(rowbase + qbaseA + fr) * NQKV + h * 64 + fg * 8];
  const unsigned short* qpB = &qkv[(rowbase + qbaseB + fr) * NQKV + h * 64 + fg * 8];
  bf16x8 qfA0 = *(const bf16x8*)(qpA);
  bf16x8 qfA1 = *(const bf16x8*)(qpA + 32);
  bf16x8 qfB0 = *(const bf16x8*)(qpB);
  bf16x8 qfB1 = *(const bf16x8*)(qpB + 32);

  int kcb = ((t & 7) * 16) ^ (((t >> 3) & 7) << 4);    // K: 128B rows, row = p*32 + (t>>3)
  int vcb = ((t & 15) * 16) ^ (((t >> 4) & 7) << 4);   // V: 256B rows, row = p*16 + (t>>4)

  const char* kgb = (const char*)qkv;
  const char* vgb = (const char*)vT;
  long ksrc0 = ((rowbase) * (long)NQKV + KOFF + (long)g * 64) * 2;
  long vsrc0 = (((long)(b * 512 + g * 64)) * LSEQ) * 2;

  auto stageK = [&](int kbase) {
    #pragma unroll
    for (int p = 0; p < 4; p++) {
      int krow = p * 32 + (t >> 3);
      gload_lds16(kgb + ksrc0 + (long)(kbase + krow) * (NQKV * 2) + kcb,
                  KT + p * 4096 + t * 16);
    }
  };
  auto stageV = [&](int kbase, char* dst) {
    #pragma unroll
    for (int p = 0; p < 4; p++) {
      int vrow = p * 16 + (t >> 4);
      gload_lds16(vgb + vsrc0 + (long)vrow * (LSEQ * 2) + kbase * 2 + vcb,
                  dst + p * 4096 + t * 16);
    }
  };

  stageK(0);
  stageV(0, VT2[0]);

  f32x4 poA[4] = {}, poB[4] = {};
  f32x4 lfA = {}, lfB = {};           // MFMA-accumulated row-sums of P (denominator)
  bf16x8 onesv;
  #pragma unroll
  for (int i = 0; i < 8; i++) onesv[i] = (__bf16)1.0f;

  int sw8 = (fr & 7) << 4;

  for (int kt = 0; kt <= qt; kt++) {
    int kbase = kt * 128;
    __syncthreads();   // B1: staged K/V landed; all waves' prev-iter LDS reads done

    // V restage WAR-safe at B1 (prev PV readers of this buffer synced); full-iter cover
    if (kt < qt) stageV(kbase + 128, VT2[(kt + 1) & 1]);

    f32x4 stA[8], stB[8];
    __builtin_amdgcn_s_setprio(1);
    #pragma unroll
    for (int s = 0; s < 8; s++) {
      const char* kr = KT + ((s * 16 + fr) << 7);
      bf16x8 kf0 = *(const bf16x8*)(kr + ((fg * 16) ^ sw8));
      bf16x8 kf1 = *(const bf16x8*)(kr + ((fg * 16 + 64) ^ sw8));
      f32x4 a = {};
      a = __builtin_amdgcn_mfma_f32_16x16x32_bf16(kf0, qfA0, a, 0, 0, 0);
      a = __builtin_amdgcn_mfma_f32_16x16x32_bf16(kf1, qfA1, a, 0, 0, 0);
      stA[s] = a;
      f32x4 c = {};
      c = __builtin_amdgcn_mfma_f32_16x16x32_bf16(kf0, qfB0, c, 0, 0, 0);
      c = __builtin_amdgcn_mfma_f32_16x16x32_bf16(kf1, qfB1, c, 0, 0, 0);
      stB[s] = c;
    }
    __builtin_amdgcn_s_setprio(0);
    __syncthreads();   // B2: all waves' K ds_reads retired -> K restage safe

    if (kt < qt) stageK(kbase + 128);   // lands by next B1; softmax+PV cover

    if (kt == qt) {   // diagonal tile: causal mask (k = kbase+s*16+fg*4+r, q = qbase+fr)
      #pragma unroll
      for (int s = 0; s < 8; s++) {
        #pragma unroll
        for (int r = 0; r < 4; r++) {
          int kp = kbase + s * 16 + fg * 4 + r;
          if (kp > qbaseA + fr) stA[s][r] = -1e30f;
          if (kp > qbaseB + fr) stB[s][r] = -1e30f;
        }
      }
    }

    // softmax (static-max, pre-scaled exp2 domain) + register-only bf16 pack.
    // A-frag slot (fg, j): j=r -> k32 = 4*fg + r ; j=4+r -> k32 = 16 + 4*fg + r.
    // No scalar l accumulation: denominator comes from the ones-MFMA below.
    bf16x8 paA[4], paB[4];
    #pragma unroll
    for (int km = 0; km < 4; km++) {
      bf16x8 pa, pb;
      #pragma unroll
      for (int r = 0; r < 4; r++) {
        pa[r]     = (__bf16)exp2f(stA[2 * km][r]);
        pa[r + 4] = (__bf16)exp2f(stA[2 * km + 1][r]);
        pb[r]     = (__bf16)exp2f(stB[2 * km][r]);
        pb[r + 4] = (__bf16)exp2f(stB[2 * km + 1][r]);
      }
      paA[km] = pa;
      paB[km] = pb;
    }

    const char* Vb = VT2[kt & 1];
    __builtin_amdgcn_s_setprio(1);
    #pragma unroll
    for (int km = 0; km < 4; km++) {
      // denominator row-sum on the matrix pipe: every col of D = sum_k P[q][k]
      lfA = __builtin_amdgcn_mfma_f32_16x16x32_bf16(paA[km], onesv, lfA, 0, 0, 0);
      lfB = __builtin_amdgcn_mfma_f32_16x16x32_bf16(paB[km], onesv, lfB, 0, 0, 0);
      #pragma unroll
      for (int dt = 0; dt < 4; dt++) {
        const char* vr = Vb + ((dt * 16 + fr) << 8);
        bf16x8 vf = *(const bf16x8*)(vr + ((km * 64 + fg * 16) ^ sw8));
        poA[dt] = __builtin_amdgcn_mfma_f32_16x16x32_bf16(paA[km], vf, poA[dt], 0, 0, 0);
        poB[dt] = __builtin_amdgcn_mfma_f32_16x16x32_bf16(paB[km], vf, poB[dt], 0, 0, 0);
      }
    }
    __builtin_amdgcn_s_setprio(0);
    // no trailing barrier: next B1 orders LDS reads vs. restaging
  }

  // denominator is lane-local: lf[r] = l for q = fg*4+r (identical on every lane's col)
  #pragma unroll
  for (int r = 0; r < 4; r++) {
    float liA = 1.0f / lfA[r];
    float liB = 1.0f / lfB[r];
    #pragma unroll
    for (int dt = 0; dt < 4; dt++) {
      attn[(rowbase + qbaseA + fg * 4 + r) * DIM + h * 64 + dt * 16 + fr] = f2bf(poA[dt][r] * liA);
      attn[(rowbase + qbaseB + fg * 4 + r) * DIM + h * 64 + dt * 16 + fr] = f2bf(poB[dt][r] * liB);
    }
  }
}

extern "C" void kernel_launch(void* const* d_in, const int* in_sizes, int n_in,
                              void* d_out, int out_size, void* d_ws, size_t ws_size,
                              hipStream_t stream) {
  const float* x  = (const float*)d_in[0];
  const float* wq = (const float*)d_in[1];
  const float* wk = (const float*)d_in[2];
  const float* wv = (const float*)d_in[3];
  const float* wo = (const float*)d_in[4];

  char* ws = (char*)d_ws;
  unsigned short* xb    = (unsigned short*)(ws);                 // 16.78 MB (reused as vT later)
  unsigned short* wqkvT = (unsigned short*)(ws + 16777216);      // 12.58 MB [3072][2048]
  unsigned short* woT   = (unsigned short*)(ws + 29360128);      //  8.39 MB [2048][2048]
  unsigned short* qkv   = (unsigned short*)(ws + 37748736);      // 25.17 MB [4096][3072]
  unsigned short* attn  = (unsigned short*)(ws + 62914560);      // 16.78 MB [4096][2048]
  float* cosT           = (float*)(ws + 79691776);               // 256 KB
  float* sinT           = (float*)(ws + 79953920);               // 256 KB
  unsigned short* vT    = xb;                                    // alias: xb dead after QKV GEMM

  const float C2 = 0.125f * 1.44269504f;   // 1/sqrt(64) * log2(e), folded into wq

  k_cvt_x<<<8192, 256, 0, stream>>>(x, xb, M_ROWS * DIM / 4);
  dim3 tb(32, 8);
  // fused weight transposes: one launch, 4 z-sections
  k_transpose_all<<<dim3(64, 64, 4), tb, 0, stream>>>(wq, wk, wv, wo, wqkvT, woT, C2);
  k_rope_table<<<(LSEQ*32)/256, 256, 0, stream>>>(cosT, sinT);

  // QKV: 128^2 BK=64, 512 threads / 8 waves (r13-verified) + fused RoPE
  k_gemm_bt<true, true><<<dim3(M_ROWS/128, NQKV/128), 512, 0, stream>>>(
      xb, wqkvT, qkv, M_ROWS, NQKV, DIM, cosT, sinT);
  k_transpose_v<<<dim3(16, 64, 2), tb, 0, stream>>>(qkv, vT);
  k_flash_attn14<<<1024, 256, 0, stream>>>(qkv, vT, attn);
  // WO: r11/r13 128^2 dbuf single-barrier pipeline, 512 threads
  k_gemm_db<<<dim3(M_ROWS/128, DIM/128), 512, 0, stream>>>(
      attn, woT, (float*)d_out, M_ROWS, DIM, DIM);
}